// Round 2
// baseline (992.558 us; speedup 1.0000x reference)
//
#include <hip/hip_runtime.h>

// ImageCaptionModel: B=128 T=32 V=10000 H=512 E=512 F=2048 NM=512
// D0=1536 D1=1024. All GEMMs bf16-MFMA (16x16x32) with fp32 accum.
// Recurrence runs in ONE persistent kernel (256 blocks, grid spin-barrier).

typedef short s8v __attribute__((ext_vector_type(8)));   // 8 x bf16 bits
typedef float f4v __attribute__((ext_vector_type(4)));   // MFMA acc

#define OUT_H 40960000   // B*T*V

__device__ __forceinline__ unsigned short f2bf(float f) {
  unsigned u = __float_as_uint(f);
  u += 0x7fffu + ((u >> 16) & 1u);          // round-to-nearest-even
  return (unsigned short)(u >> 16);
}
__device__ __forceinline__ float sigm(float x) { return 1.0f / (1.0f + __expf(-x)); }
__device__ __forceinline__ float tanh_(float x) { return 1.0f - 2.0f / (1.0f + __expf(2.0f * x)); }

__device__ __forceinline__ void glds16(const unsigned short* g, unsigned short* l) {
  __builtin_amdgcn_global_load_lds((const __attribute__((address_space(1))) void*)g,
                                   (__attribute__((address_space(3))) void*)l, 16, 0, 0);
}

// ---- transpose + fp32->bf16: dst[c][r] = src[r][c] ----
__global__ void k_transpose_cvt(const float* __restrict__ src, unsigned short* __restrict__ dst,
                                int R, int C) {
  __shared__ float tile[32][33];
  int c0 = blockIdx.x * 32, r0 = blockIdx.y * 32;
  int tx = threadIdx.x, ty = threadIdx.y;
#pragma unroll
  for (int i = 0; i < 4; i++) {
    int r = r0 + ty + i * 8, c = c0 + tx;
    if (r < R && c < C) tile[ty + i * 8][tx] = src[(size_t)r * C + c];
  }
  __syncthreads();
#pragma unroll
  for (int i = 0; i < 4; i++) {
    int c = c0 + ty + i * 8, r = r0 + tx;
    if (r < R && c < C) dst[(size_t)c * R + r] = f2bf(tile[tx][ty + i * 8]);
  }
}

// ---- fp32 -> bf16 (vec4) ----
__global__ void k_cvt_bf16(const float* __restrict__ in, unsigned short* __restrict__ out, int n4) {
  int i = blockIdx.x * 256 + threadIdx.x;
  if (i >= n4) return;
  float4 v = ((const float4*)in)[i];
  ushort4 p; p.x = f2bf(v.x); p.y = f2bf(v.y); p.z = f2bf(v.z); p.w = f2bf(v.w);
  ((ushort4*)out)[i] = p;
}

// ---- embedding gather -> Xe[t*128+b][512] bf16 ----
__global__ void k_gather_emb(const float* __restrict__ emb, const int* __restrict__ tok,
                             unsigned short* __restrict__ Xe) {
  int i = blockIdx.x * 256 + threadIdx.x;  // 4096*512/4 = 524288
  int r = i >> 7, k4 = (i & 127) * 4;
  int b = r & 127, t = r >> 7;
  int tk = tok[b * 32 + t];
  float4 v = *(const float4*)(emb + (size_t)tk * 512 + k4);
  ushort4 p; p.x = f2bf(v.x); p.y = f2bf(v.y); p.z = f2bf(v.z); p.w = f2bf(v.w);
  ((ushort4*)Xe)[i] = p;
}

// ---- init bf16 h-state + zero barrier slots ----
__global__ void k_init2(const float* __restrict__ chs,
                        unsigned short* __restrict__ h0b1, unsigned short* __restrict__ h1b1,
                        int* __restrict__ bar) {
  int i = blockIdx.x * 256 + threadIdx.x;  // 65536
  int b = i >> 9, j = i & 511;
  h0b1[i] = f2bf(chs[b * 1024 + j]);
  h1b1[i] = f2bf(chs[131072 + b * 1024 + j]);
  if (i < 4096) bar[i] = 0;   // 256 slots x 16-int padding
}

// ---- generic 128x128-tile GEMM: C[M][N] = A[M][K] * Bt[N][K]^T (+epilogue) ----
// MODE 0: proc  = leaky(acc + bias) -> outB (bf16)
// MODE 1: Cf    = acc + bias        -> outF
// MODE 2: Zx    = acc + add128[m&127][n] -> outF
// MODE 3: logit = acc + bias -> out[(b*32+t)*N + n], b=m&127, t=m>>7 (N ragged)
template <int MODE>
__global__ __launch_bounds__(256, 2)
void k_gemm(const unsigned short* __restrict__ A, const unsigned short* __restrict__ Bt,
            const float* __restrict__ bias, const float* __restrict__ add128,
            float* __restrict__ outF, unsigned short* __restrict__ outB,
            int M, int N, int K) {
  __shared__ unsigned short As[4096];  // 128 x 32
  __shared__ unsigned short Bs[4096];
  int tid = threadIdx.x;
  int wave = tid >> 6, lane = tid & 63;
  int lr = lane & 15, lq = lane >> 4;
  int wm = (wave >> 1) * 64, wn = (wave & 1) * 64;
  int m0 = blockIdx.y * 128, n0 = blockIdx.x * 128;

  f4v acc[4][4];
  f4v zero = {0.0f, 0.0f, 0.0f, 0.0f};
#pragma unroll
  for (int i = 0; i < 4; i++)
#pragma unroll
    for (int j = 0; j < 4; j++) acc[i][j] = zero;

  int srow = tid >> 2, sofs = (tid & 3) * 8;
  int ar0 = m0 + srow, ar1 = ar0 + 64;
  int br0 = n0 + srow, br1 = br0 + 64;
  if (br0 >= N) br0 = N - 1;   // ragged-N clamp (logits); masked in epilogue
  if (br1 >= N) br1 = N - 1;
  const unsigned short* Ag0 = A + (size_t)ar0 * K + sofs;
  const unsigned short* Ag1 = A + (size_t)ar1 * K + sofs;
  const unsigned short* Bg0 = Bt + (size_t)br0 * K + sofs;
  const unsigned short* Bg1 = Bt + (size_t)br1 * K + sofs;
  unsigned short* lA0 = &As[tid * 8];
  unsigned short* lA1 = &As[2048 + tid * 8];
  unsigned short* lB0 = &Bs[tid * 8];
  unsigned short* lB1 = &Bs[2048 + tid * 8];

  for (int k0 = 0; k0 < K; k0 += 32) {
    glds16(Ag0 + k0, lA0);
    glds16(Ag1 + k0, lA1);
    glds16(Bg0 + k0, lB0);
    glds16(Bg1 + k0, lB1);
    __syncthreads();
    s8v af[4], bfr[4];
#pragma unroll
    for (int i = 0; i < 4; i++) af[i] = *(const s8v*)&As[(wm + i * 16 + lr) * 32 + lq * 8];
#pragma unroll
    for (int i = 0; i < 4; i++) bfr[i] = *(const s8v*)&Bs[(wn + i * 16 + lr) * 32 + lq * 8];
#pragma unroll
    for (int i = 0; i < 4; i++)
#pragma unroll
      for (int j = 0; j < 4; j++)
        acc[i][j] = __builtin_amdgcn_mfma_f32_16x16x32_bf16(af[i], bfr[j], acc[i][j], 0, 0, 0);
    __syncthreads();
  }

#pragma unroll
  for (int i = 0; i < 4; i++) {
#pragma unroll
    for (int j = 0; j < 4; j++) {
      int nn = n0 + wn + j * 16 + lr;       // C/D: col = lane&15
      if (nn >= N) continue;
#pragma unroll
      for (int r = 0; r < 4; r++) {
        int mm = m0 + wm + i * 16 + lq * 4 + r;  // C/D: row = (lane>>4)*4+reg
        float v = acc[i][j][r];
        if (MODE == 0) {
          v += bias[nn];
          v = v > 0.0f ? v : 0.01f * v;
          outB[(size_t)mm * N + nn] = f2bf(v);
        } else if (MODE == 1) {
          v += bias[nn];
          outF[(size_t)mm * N + nn] = v;
        } else if (MODE == 2) {
          v += add128[(size_t)(mm & 127) * N + nn];
          outF[(size_t)mm * N + nn] = v;
        } else {
          v += bias[nn];
          int b = mm & 127, t = mm >> 7;
          outF[(size_t)(b * 32 + t) * N + nn] = v;
        }
      }
    }
  }
}

// ---- K-slice partial GEMM for one wave: acc[mtl][g] over NKC k-chunks ----
template <int NKC>
__device__ __forceinline__ void pmm(const unsigned short* __restrict__ hA,
                                    const unsigned short* __restrict__ w0,
                                    const unsigned short* __restrict__ w1,
                                    const unsigned short* __restrict__ w2,
                                    const unsigned short* __restrict__ w3,
                                    int am0, int am1, int ko, f4v acc[2][4]) {
#pragma unroll
  for (int kc = 0; kc < NKC; kc++) {
    int kk = kc * 32 + ko;
    s8v a0 = *(const s8v*)(hA + am0 * 512 + kk);
    s8v a1 = *(const s8v*)(hA + am1 * 512 + kk);
    s8v b0 = *(const s8v*)(w0 + kk);
    s8v b1 = *(const s8v*)(w1 + kk);
    s8v b2 = *(const s8v*)(w2 + kk);
    s8v b3 = *(const s8v*)(w3 + kk);
    acc[0][0] = __builtin_amdgcn_mfma_f32_16x16x32_bf16(a0, b0, acc[0][0], 0, 0, 0);
    acc[1][0] = __builtin_amdgcn_mfma_f32_16x16x32_bf16(a1, b0, acc[1][0], 0, 0, 0);
    acc[0][1] = __builtin_amdgcn_mfma_f32_16x16x32_bf16(a0, b1, acc[0][1], 0, 0, 0);
    acc[1][1] = __builtin_amdgcn_mfma_f32_16x16x32_bf16(a1, b1, acc[1][1], 0, 0, 0);
    acc[0][2] = __builtin_amdgcn_mfma_f32_16x16x32_bf16(a0, b2, acc[0][2], 0, 0, 0);
    acc[1][2] = __builtin_amdgcn_mfma_f32_16x16x32_bf16(a1, b2, acc[1][2], 0, 0, 0);
    acc[0][3] = __builtin_amdgcn_mfma_f32_16x16x32_bf16(a0, b3, acc[0][3], 0, 0, 0);
    acc[1][3] = __builtin_amdgcn_mfma_f32_16x16x32_bf16(a1, b3, acc[1][3], 0, 0, 0);
  }
}

// ---- grid spin-barrier: per-block generation slots (64B-padded), agent scope ----
__device__ __forceinline__ void gridbar(int* bar, int gen) {
  __syncthreads();
  if (threadIdx.x == 0) {
    __threadfence();   // release: drain + L2 writeback (cross-XCD visibility)
    __hip_atomic_store(&bar[blockIdx.x * 16], gen, __ATOMIC_RELAXED, __HIP_MEMORY_SCOPE_AGENT);
  }
  // 256 threads poll 256 distinct slots in parallel
  while (__hip_atomic_load(&bar[threadIdx.x * 16], __ATOMIC_RELAXED, __HIP_MEMORY_SCOPE_AGENT) < gen) {}
  __syncthreads();
  if (threadIdx.x == 0) __threadfence();  // acquire: invalidate stale L1/L2 lines
  __syncthreads();
}

// ---- persistent LSTM recurrence: 33 phases, one kernel ----
// Blocks [0,128): B-groups (z1 = [h0n|h1]@W1 + b1 -> h1n,c1n, H1all)
// Blocks [128,256): A-groups (z0 = Zx[t] + h0@W0h  -> h0n,c0n)
// Block = (jt, mh): 16 n-cols x 4 gates, 32 m-rows. Waves = K-quarters.
// c-state lives in registers of waves 0/1 for the whole sequence.
__global__ __launch_bounds__(256, 2)
void k_lstm(const unsigned short* __restrict__ W0h_t, const unsigned short* __restrict__ W1_t,
            const float* __restrict__ Zx, const float* __restrict__ b1,
            const float* __restrict__ chs,
            unsigned short* __restrict__ h0b0, unsigned short* __restrict__ h0b1,
            unsigned short* __restrict__ h1b0, unsigned short* __restrict__ h1b1,
            unsigned short* __restrict__ H1all, float* __restrict__ outHid,
            int* __restrict__ bar) {
  __shared__ f4v part[8][4][64];   // [kq*2+mtl][g][lane] = 32 KB
  int tid = threadIdx.x;
  int wave = tid >> 6, lane = tid & 63;
  int lr = lane & 15, lq = lane >> 4;
  int bb = blockIdx.x;
  bool isB = bb < 128;
  int gb = isB ? bb : bb - 128;
  int jt = gb >> 2, mh = gb & 3;
  int kq = wave;
  int j = jt * 16 + lr;
  int Kfull = isB ? 1024 : 512;
  int kbase = kq * (Kfull >> 2);
  int am0 = (mh * 2) * 16 + lr;        // A-operand rows (lane&15)
  int am1 = (mh * 2 + 1) * 16 + lr;
  int me_base = (mh * 2 + wave) * 16 + lq * 4;  // epilogue rows (waves 0,1)

  const unsigned short* Wt = isB ? W1_t : W0h_t;
  const unsigned short* wg0 = Wt + (size_t)(0 * 512 + jt * 16 + lr) * Kfull + kbase;
  const unsigned short* wg1 = Wt + (size_t)(1 * 512 + jt * 16 + lr) * Kfull + kbase;
  const unsigned short* wg2 = Wt + (size_t)(2 * 512 + jt * 16 + lr) * Kfull + kbase;
  const unsigned short* wg3 = Wt + (size_t)(3 * 512 + jt * 16 + lr) * Kfull + kbase;

  // register c-state + biases (waves 0,1 only)
  float cs[4] = {0, 0, 0, 0};
  float bi = 0, bo = 0, bf_ = 0, bc = 0;
  if (wave < 2) {
    int coff = isB ? 131072 : 0;
#pragma unroll
    for (int r = 0; r < 4; r++) cs[r] = chs[coff + (size_t)(me_base + r) * 1024 + 512 + j];
    if (isB) { bi = b1[j]; bo = b1[512 + j]; bf_ = b1[1024 + j]; bc = b1[1536 + j]; }
  }

  for (int p = 0; p <= 32; p++) {
    int t = isB ? (p - 1) : p;
    bool active = isB ? (p >= 1) : (p <= 31);
    f4v acc[2][4];
    if (active) {
      const unsigned short* hA;
      if (isB) {
        const unsigned short* h0r = (t & 1) ? h0b1 : h0b0;   // h0buf[t&1]
        const unsigned short* h1r = (t & 1) ? h1b0 : h1b1;   // h1buf[(t+1)&1]
        hA = (kbase < 512) ? (h0r + kbase) : (h1r + kbase - 512);
      } else {
        hA = ((t & 1) ? h0b0 : h0b1) + kbase;                // h0buf[(t+1)&1]
      }
      f4v zero = {0.0f, 0.0f, 0.0f, 0.0f};
#pragma unroll
      for (int i = 0; i < 2; i++)
#pragma unroll
        for (int g = 0; g < 4; g++) acc[i][g] = zero;
      if (isB) pmm<8>(hA, wg0, wg1, wg2, wg3, am0, am1, lq * 8, acc);
      else     pmm<4>(hA, wg0, wg1, wg2, wg3, am0, am1, lq * 8, acc);
#pragma unroll
      for (int i = 0; i < 2; i++)
#pragma unroll
        for (int g = 0; g < 4; g++) part[kq * 2 + i][g][lane] = acc[i][g];
    }
    __syncthreads();
    if (active && wave < 2) {
      f4v z[4];
#pragma unroll
      for (int g = 0; g < 4; g++) {
        f4v s = part[wave][g][lane];
        s += part[2 + wave][g][lane];
        s += part[4 + wave][g][lane];
        s += part[6 + wave][g][lane];
        z[g] = s;
      }
      unsigned short* hw;
      if (isB) hw = (t & 1) ? h1b1 : h1b0;      // h1buf[t&1]
      else     hw = (t & 1) ? h0b1 : h0b0;      // h0buf[t&1]
#pragma unroll
      for (int r = 0; r < 4; r++) {
        int m = me_base + r;
        float zi, zo, zf, zc;
        if (isB) {
          zi = z[0][r] + bi; zo = z[1][r] + bo; zf = z[2][r] + bf_; zc = z[3][r] + bc;
        } else {
          const float* zrow = Zx + (size_t)t * 262144 + (size_t)m * 2048;
          zi = z[0][r] + zrow[j];        zo = z[1][r] + zrow[512 + j];
          zf = z[2][r] + zrow[1024 + j]; zc = z[3][r] + zrow[1536 + j];
        }
        float iv = sigm(zi), ov = sigm(zo), fv = sigm(zf), cv = tanh_(zc);
        float cn = fv * cs[r] + iv * cv;
        float hn = ov * tanh_(cn);
        cs[r] = cn;
        unsigned short hb = f2bf(hn);
        hw[m * 512 + j] = hb;
        if (isB) H1all[((size_t)t * 128 + m) * 512 + j] = hb;
        if (t == 31) {
          size_t o = OUT_H + (isB ? 131072 : 0) + (size_t)m * 1024;
          outHid[o + j] = hn;
          outHid[o + 512 + j] = cn;
        }
      }
    }
    if (p < 32) gridbar(bar, p + 1);
  }
}

extern "C" void kernel_launch(void* const* d_in, const int* in_sizes, int n_in,
                              void* d_out, int out_size, void* d_ws, size_t ws_size,
                              hipStream_t stream) {
  const float* cnn  = (const float*)d_in[0];
  const int*   tok  = (const int*)d_in[1];
  const float* chs  = (const float*)d_in[2];
  const float* emb  = (const float*)d_in[3];
  const float* W_in = (const float*)d_in[4];
  const float* b_in = (const float*)d_in[5];
  const float* W0   = (const float*)d_in[6];
  const float* b0   = (const float*)d_in[7];
  const float* W1   = (const float*)d_in[8];
  const float* b1   = (const float*)d_in[9];
  const float* W_out= (const float*)d_in[10];
  const float* b_out= (const float*)d_in[11];
  float* out = (float*)d_out;

  char* p = (char*)d_ws;
  auto alloc = [&](size_t bytes) { char* q = p; p += (bytes + 255) & ~(size_t)255; return q; };
  unsigned short* Win_t  = (unsigned short*)alloc((size_t)512 * 2048 * 2);
  unsigned short* W0e_t  = (unsigned short*)alloc((size_t)2048 * 512 * 2);
  unsigned short* W0m_t  = (unsigned short*)alloc((size_t)2048 * 512 * 2);
  unsigned short* W0h_t  = (unsigned short*)alloc((size_t)2048 * 512 * 2);
  unsigned short* W1_t   = (unsigned short*)alloc((size_t)2048 * 1024 * 2);
  unsigned short* Wout_t = (unsigned short*)alloc((size_t)10000 * 512 * 2);
  unsigned short* cnn_b  = (unsigned short*)alloc((size_t)128 * 2048 * 2);
  unsigned short* proc_b = (unsigned short*)alloc((size_t)128 * 512 * 2);
  float*          Cf     = (float*)alloc((size_t)128 * 2048 * 4);
  unsigned short* Xe     = (unsigned short*)alloc((size_t)4096 * 512 * 2);
  float*          Zx     = (float*)alloc((size_t)4096 * 2048 * 4);
  unsigned short* h0b0   = (unsigned short*)alloc(65536 * 2);
  unsigned short* h0b1   = (unsigned short*)alloc(65536 * 2);
  unsigned short* h1b0   = (unsigned short*)alloc(65536 * 2);
  unsigned short* h1b1   = (unsigned short*)alloc(65536 * 2);
  unsigned short* H1all  = (unsigned short*)alloc((size_t)4096 * 512 * 2);
  int*            bar    = (int*)alloc(4096 * 4);   // 256 slots x 16-int pad

  dim3 tb(32, 8);
  k_transpose_cvt<<<dim3(16, 64),  tb, 0, stream>>>(W_in, Win_t, 2048, 512);
  k_transpose_cvt<<<dim3(64, 16),  tb, 0, stream>>>(W0,               W0e_t, 512, 2048);
  k_transpose_cvt<<<dim3(64, 16),  tb, 0, stream>>>(W0 + 512 * 2048,  W0m_t, 512, 2048);
  k_transpose_cvt<<<dim3(64, 16),  tb, 0, stream>>>(W0 + 1024 * 2048, W0h_t, 512, 2048);
  k_transpose_cvt<<<dim3(64, 32),  tb, 0, stream>>>(W1, W1_t, 1024, 2048);
  k_transpose_cvt<<<dim3(313, 16), tb, 0, stream>>>(W_out, Wout_t, 512, 10000);
  k_cvt_bf16<<<256, 256, 0, stream>>>(cnn, cnn_b, 65536);

  // proc = leaky(cnn @ W_in + b_in)  (bf16 out)
  k_gemm<0><<<dim3(4, 1), 256, 0, stream>>>(cnn_b, Win_t, b_in, nullptr, nullptr, proc_b,
                                            128, 512, 2048);
  // Cf = proc @ W0[512:1024] + b0  (fp32, per-batch broadcast term of Zx)
  k_gemm<1><<<dim3(16, 1), 256, 0, stream>>>(proc_b, W0m_t, b0, nullptr, Cf, nullptr,
                                             128, 2048, 512);
  k_gather_emb<<<2048, 256, 0, stream>>>(emb, tok, Xe);
  // Zx[t*128+b] = emb_t @ W0[0:512] + Cf[b]
  k_gemm<2><<<dim3(16, 32), 256, 0, stream>>>(Xe, W0e_t, nullptr, Cf, Zx, nullptr,
                                              4096, 2048, 512);
  k_init2<<<256, 256, 0, stream>>>(chs, h0b1, h1b1, bar);

  // whole recurrence: one persistent kernel, 33 phases, 32 grid barriers
  k_lstm<<<256, 256, 0, stream>>>(W0h_t, W1_t, Zx, b1, chs,
                                  h0b0, h0b1, h1b0, h1b1, H1all, out, bar);

  // logits = H1all @ W_out + b_out  -> d_out[(b*32+t)*10000 + v]
  k_gemm<3><<<dim3(79, 32), 256, 0, stream>>>(H1all, Wout_t, b_out, nullptr, out, nullptr,
                                              4096, 10000, 512);
}

// Round 3
// 873.080 us; speedup vs baseline: 1.1368x; 1.1368x over previous
//
#include <hip/hip_runtime.h>

// ImageCaptionModel: B=128 T=32 V=10000 H=512 E=512 F=2048 NM=512
// D0=1536 D1=1024. All GEMMs bf16-MFMA (16x16x32) with fp32 accum.
// Recurrence: ONE persistent kernel, 256 blocks, fence-free grid barrier.
// Cross-XCD h-state exchange via relaxed agent-scope atomics (sc1 => coherent
// at L3, no buffer_inv/wbl2) so weights stay L2-resident across all phases.

typedef short s8v __attribute__((ext_vector_type(8)));   // 8 x bf16 bits
typedef float f4v __attribute__((ext_vector_type(4)));   // MFMA acc

#define OUT_H 40960000   // B*T*V

__device__ __forceinline__ unsigned short f2bf(float f) {
  unsigned u = __float_as_uint(f);
  u += 0x7fffu + ((u >> 16) & 1u);          // round-to-nearest-even
  return (unsigned short)(u >> 16);
}
__device__ __forceinline__ float sigm(float x) { return 1.0f / (1.0f + __expf(-x)); }
__device__ __forceinline__ float tanh_(float x) { return 1.0f - 2.0f / (1.0f + __expf(2.0f * x)); }

__device__ __forceinline__ void glds16(const unsigned short* g, unsigned short* l) {
  __builtin_amdgcn_global_load_lds((const __attribute__((address_space(1))) void*)g,
                                   (__attribute__((address_space(3))) void*)l, 16, 0, 0);
}

// 8 consecutive fp32 h-values via agent-scope (sc1) relaxed atomic loads,
// converted to a bf16x8 MFMA A-fragment. Bypasses (possibly stale) L1/L2.
__device__ __forceinline__ s8v load_h8(const float* p) {
  unsigned long long q[4];
#pragma unroll
  for (int i = 0; i < 4; i++)
    q[i] = __hip_atomic_load((const unsigned long long*)p + i,
                             __ATOMIC_RELAXED, __HIP_MEMORY_SCOPE_AGENT);
  s8v r;
#pragma unroll
  for (int i = 0; i < 4; i++) {
    r[2 * i]     = (short)f2bf(__uint_as_float((unsigned)(q[i] & 0xffffffffull)));
    r[2 * i + 1] = (short)f2bf(__uint_as_float((unsigned)(q[i] >> 32)));
  }
  return r;
}

// ---- transpose + fp32->bf16: dst[c][r] = src[r][c] ----
__global__ void k_transpose_cvt(const float* __restrict__ src, unsigned short* __restrict__ dst,
                                int R, int C) {
  __shared__ float tile[32][33];
  int c0 = blockIdx.x * 32, r0 = blockIdx.y * 32;
  int tx = threadIdx.x, ty = threadIdx.y;
#pragma unroll
  for (int i = 0; i < 4; i++) {
    int r = r0 + ty + i * 8, c = c0 + tx;
    if (r < R && c < C) tile[ty + i * 8][tx] = src[(size_t)r * C + c];
  }
  __syncthreads();
#pragma unroll
  for (int i = 0; i < 4; i++) {
    int c = c0 + ty + i * 8, r = r0 + tx;
    if (r < R && c < C) dst[(size_t)c * R + r] = f2bf(tile[tx][ty + i * 8]);
  }
}

// ---- fp32 -> bf16 (vec4) ----
__global__ void k_cvt_bf16(const float* __restrict__ in, unsigned short* __restrict__ out, int n4) {
  int i = blockIdx.x * 256 + threadIdx.x;
  if (i >= n4) return;
  float4 v = ((const float4*)in)[i];
  ushort4 p; p.x = f2bf(v.x); p.y = f2bf(v.y); p.z = f2bf(v.z); p.w = f2bf(v.w);
  ((ushort4*)out)[i] = p;
}

// ---- embedding gather -> Xe[t*128+b][512] bf16 ----
__global__ void k_gather_emb(const float* __restrict__ emb, const int* __restrict__ tok,
                             unsigned short* __restrict__ Xe) {
  int i = blockIdx.x * 256 + threadIdx.x;  // 4096*512/4 = 524288
  int r = i >> 7, k4 = (i & 127) * 4;
  int b = r & 127, t = r >> 7;
  int tk = tok[b * 32 + t];
  float4 v = *(const float4*)(emb + (size_t)tk * 512 + k4);
  ushort4 p; p.x = f2bf(v.x); p.y = f2bf(v.y); p.z = f2bf(v.z); p.w = f2bf(v.w);
  ((ushort4*)Xe)[i] = p;
}

// ---- init fp32 h-state buffers + zero barrier slots ----
__global__ void k_init2(const float* __restrict__ chs,
                        float* __restrict__ h0b1, float* __restrict__ h1b1,
                        int* __restrict__ bar) {
  int i = blockIdx.x * 256 + threadIdx.x;  // 65536
  int b = i >> 9, j = i & 511;
  h0b1[i] = chs[b * 1024 + j];
  h1b1[i] = chs[131072 + b * 1024 + j];
  if (i < 4096) bar[i] = 0;   // 256 slots x 16-int padding
}

// ---- generic 128x128-tile GEMM: C[M][N] = A[M][K] * Bt[N][K]^T (+epilogue) ----
// MODE 0: proc  = leaky(acc + bias) -> outB (bf16)
// MODE 1: Cf    = acc + bias        -> outF
// MODE 2: Zx    = acc + add128[m&127][n] -> outF
// MODE 3: logit = acc + bias -> out[(b*32+t)*N + n], b=m&127, t=m>>7 (N ragged)
template <int MODE>
__global__ __launch_bounds__(256, 2)
void k_gemm(const unsigned short* __restrict__ A, const unsigned short* __restrict__ Bt,
            const float* __restrict__ bias, const float* __restrict__ add128,
            float* __restrict__ outF, unsigned short* __restrict__ outB,
            int M, int N, int K) {
  __shared__ unsigned short As[4096];  // 128 x 32
  __shared__ unsigned short Bs[4096];
  int tid = threadIdx.x;
  int wave = tid >> 6, lane = tid & 63;
  int lr = lane & 15, lq = lane >> 4;
  int wm = (wave >> 1) * 64, wn = (wave & 1) * 64;
  int m0 = blockIdx.y * 128, n0 = blockIdx.x * 128;

  f4v acc[4][4];
  f4v zero = {0.0f, 0.0f, 0.0f, 0.0f};
#pragma unroll
  for (int i = 0; i < 4; i++)
#pragma unroll
    for (int j = 0; j < 4; j++) acc[i][j] = zero;

  int srow = tid >> 2, sofs = (tid & 3) * 8;
  int ar0 = m0 + srow, ar1 = ar0 + 64;
  int br0 = n0 + srow, br1 = br0 + 64;
  if (br0 >= N) br0 = N - 1;   // ragged-N clamp (logits); masked in epilogue
  if (br1 >= N) br1 = N - 1;
  const unsigned short* Ag0 = A + (size_t)ar0 * K + sofs;
  const unsigned short* Ag1 = A + (size_t)ar1 * K + sofs;
  const unsigned short* Bg0 = Bt + (size_t)br0 * K + sofs;
  const unsigned short* Bg1 = Bt + (size_t)br1 * K + sofs;
  unsigned short* lA0 = &As[tid * 8];
  unsigned short* lA1 = &As[2048 + tid * 8];
  unsigned short* lB0 = &Bs[tid * 8];
  unsigned short* lB1 = &Bs[2048 + tid * 8];

  for (int k0 = 0; k0 < K; k0 += 32) {
    glds16(Ag0 + k0, lA0);
    glds16(Ag1 + k0, lA1);
    glds16(Bg0 + k0, lB0);
    glds16(Bg1 + k0, lB1);
    __syncthreads();
    s8v af[4], bfr[4];
#pragma unroll
    for (int i = 0; i < 4; i++) af[i] = *(const s8v*)&As[(wm + i * 16 + lr) * 32 + lq * 8];
#pragma unroll
    for (int i = 0; i < 4; i++) bfr[i] = *(const s8v*)&Bs[(wn + i * 16 + lr) * 32 + lq * 8];
#pragma unroll
    for (int i = 0; i < 4; i++)
#pragma unroll
      for (int j = 0; j < 4; j++)
        acc[i][j] = __builtin_amdgcn_mfma_f32_16x16x32_bf16(af[i], bfr[j], acc[i][j], 0, 0, 0);
    __syncthreads();
  }

#pragma unroll
  for (int i = 0; i < 4; i++) {
#pragma unroll
    for (int j = 0; j < 4; j++) {
      int nn = n0 + wn + j * 16 + lr;       // C/D: col = lane&15
      if (nn >= N) continue;
#pragma unroll
      for (int r = 0; r < 4; r++) {
        int mm = m0 + wm + i * 16 + lq * 4 + r;  // C/D: row = (lane>>4)*4+reg
        float v = acc[i][j][r];
        if (MODE == 0) {
          v += bias[nn];
          v = v > 0.0f ? v : 0.01f * v;
          outB[(size_t)mm * N + nn] = f2bf(v);
        } else if (MODE == 1) {
          v += bias[nn];
          outF[(size_t)mm * N + nn] = v;
        } else if (MODE == 2) {
          v += add128[(size_t)(mm & 127) * N + nn];
          outF[(size_t)mm * N + nn] = v;
        } else {
          v += bias[nn];
          int b = mm & 127, t = mm >> 7;
          outF[(size_t)(b * 32 + t) * N + nn] = v;
        }
      }
    }
  }
}

// ---- K-slice partial GEMM for one wave (A from fp32 h-state via sc1 loads) ----
template <int NKC>
__device__ __forceinline__ void pmm(const float* __restrict__ hA,
                                    const unsigned short* __restrict__ w0,
                                    const unsigned short* __restrict__ w1,
                                    const unsigned short* __restrict__ w2,
                                    const unsigned short* __restrict__ w3,
                                    int am0, int am1, int ko, f4v acc[2][4]) {
#pragma unroll
  for (int kc = 0; kc < NKC; kc++) {
    int kk = kc * 32 + ko;
    s8v a0 = load_h8(hA + am0 * 512 + kk);
    s8v a1 = load_h8(hA + am1 * 512 + kk);
    s8v b0 = *(const s8v*)(w0 + kk);
    s8v b1 = *(const s8v*)(w1 + kk);
    s8v b2 = *(const s8v*)(w2 + kk);
    s8v b3 = *(const s8v*)(w3 + kk);
    acc[0][0] = __builtin_amdgcn_mfma_f32_16x16x32_bf16(a0, b0, acc[0][0], 0, 0, 0);
    acc[1][0] = __builtin_amdgcn_mfma_f32_16x16x32_bf16(a1, b0, acc[1][0], 0, 0, 0);
    acc[0][1] = __builtin_amdgcn_mfma_f32_16x16x32_bf16(a0, b1, acc[0][1], 0, 0, 0);
    acc[1][1] = __builtin_amdgcn_mfma_f32_16x16x32_bf16(a1, b1, acc[1][1], 0, 0, 0);
    acc[0][2] = __builtin_amdgcn_mfma_f32_16x16x32_bf16(a0, b2, acc[0][2], 0, 0, 0);
    acc[1][2] = __builtin_amdgcn_mfma_f32_16x16x32_bf16(a1, b2, acc[1][2], 0, 0, 0);
    acc[0][3] = __builtin_amdgcn_mfma_f32_16x16x32_bf16(a0, b3, acc[0][3], 0, 0, 0);
    acc[1][3] = __builtin_amdgcn_mfma_f32_16x16x32_bf16(a1, b3, acc[1][3], 0, 0, 0);
  }
}

// ---- fence-free grid barrier ----
// __syncthreads() drains each wave's vmcnt (sc1 store acks = coherence point),
// flag store + polls are relaxed agent-scope (sc1) => no buffer_inv/wbl2,
// weights stay L2-resident. All cross-block data uses sc1 accesses.
__device__ __forceinline__ void gridbar(int* bar, int gen) {
  __syncthreads();
  if (threadIdx.x == 0)
    __hip_atomic_store(&bar[blockIdx.x * 16], gen, __ATOMIC_RELAXED, __HIP_MEMORY_SCOPE_AGENT);
  while (__hip_atomic_load(&bar[threadIdx.x * 16], __ATOMIC_RELAXED,
                           __HIP_MEMORY_SCOPE_AGENT) < gen)
    __builtin_amdgcn_s_sleep(1);
  __syncthreads();
}

// ---- persistent LSTM recurrence: 33 phases, one kernel ----
// Blocks [0,128): B-groups (z1 = [h0n|h1]@W1 + b1 -> h1n,c1n, H1all)
// Blocks [128,256): A-groups (z0 = Zx[t] + h0@W0h  -> h0n,c0n)
// Block = (jt, mh): 16 n-cols x 4 gates, 32 m-rows. Waves = K-quarters.
// c-state lives in registers of waves 0/1 for the whole sequence.
__global__ __launch_bounds__(256, 2)
void k_lstm(const unsigned short* __restrict__ W0h_t, const unsigned short* __restrict__ W1_t,
            const float* __restrict__ Zx, const float* __restrict__ b1,
            const float* __restrict__ chs,
            float* __restrict__ h0b0, float* __restrict__ h0b1,
            float* __restrict__ h1b0, float* __restrict__ h1b1,
            unsigned short* __restrict__ H1all, float* __restrict__ outHid,
            int* __restrict__ bar) {
  __shared__ f4v part[8][4][64];   // [kq*2+mtl][g][lane] = 32 KB
  int tid = threadIdx.x;
  int wave = tid >> 6, lane = tid & 63;
  int lr = lane & 15, lq = lane >> 4;
  int bb = blockIdx.x;
  bool isB = bb < 128;
  int gb = isB ? bb : bb - 128;
  int jt = gb >> 2, mh = gb & 3;
  int kq = wave;
  int j = jt * 16 + lr;
  int Kfull = isB ? 1024 : 512;
  int kbase = kq * (Kfull >> 2);
  int am0 = (mh * 2) * 16 + lr;        // A-operand rows (lane&15)
  int am1 = (mh * 2 + 1) * 16 + lr;
  int me_base = (mh * 2 + wave) * 16 + lq * 4;  // epilogue rows (waves 0,1)

  const unsigned short* Wt = isB ? W1_t : W0h_t;
  const unsigned short* wg0 = Wt + (size_t)(0 * 512 + jt * 16 + lr) * Kfull + kbase;
  const unsigned short* wg1 = Wt + (size_t)(1 * 512 + jt * 16 + lr) * Kfull + kbase;
  const unsigned short* wg2 = Wt + (size_t)(2 * 512 + jt * 16 + lr) * Kfull + kbase;
  const unsigned short* wg3 = Wt + (size_t)(3 * 512 + jt * 16 + lr) * Kfull + kbase;

  // register c-state + biases (waves 0,1 only)
  float cs[4] = {0, 0, 0, 0};
  float bi = 0, bo = 0, bf_ = 0, bc = 0;
  if (wave < 2) {
    int coff = isB ? 131072 : 0;
#pragma unroll
    for (int r = 0; r < 4; r++) cs[r] = chs[coff + (size_t)(me_base + r) * 1024 + 512 + j];
    if (isB) { bi = b1[j]; bo = b1[512 + j]; bf_ = b1[1024 + j]; bc = b1[1536 + j]; }
  }

  for (int p = 0; p <= 32; p++) {
    int t = isB ? (p - 1) : p;
    bool active = isB ? (p >= 1) : (p <= 31);
    f4v acc[2][4];
    if (active) {
      const float* hA;
      if (isB) {
        const float* h0r = (t & 1) ? h0b1 : h0b0;   // h0buf[t&1]
        const float* h1r = (t & 1) ? h1b0 : h1b1;   // h1buf[(t+1)&1]
        hA = (kbase < 512) ? (h0r + kbase) : (h1r + kbase - 512);
      } else {
        hA = ((t & 1) ? h0b0 : h0b1) + kbase;       // h0buf[(t+1)&1]
      }
      f4v zero = {0.0f, 0.0f, 0.0f, 0.0f};
#pragma unroll
      for (int i = 0; i < 2; i++)
#pragma unroll
        for (int g = 0; g < 4; g++) acc[i][g] = zero;
      if (isB) pmm<8>(hA, wg0, wg1, wg2, wg3, am0, am1, lq * 8, acc);
      else     pmm<4>(hA, wg0, wg1, wg2, wg3, am0, am1, lq * 8, acc);
#pragma unroll
      for (int i = 0; i < 2; i++)
#pragma unroll
        for (int g = 0; g < 4; g++) part[kq * 2 + i][g][lane] = acc[i][g];
    }
    __syncthreads();
    if (active && wave < 2) {
      f4v z[4];
#pragma unroll
      for (int g = 0; g < 4; g++) {
        f4v s = part[wave][g][lane];
        s += part[2 + wave][g][lane];
        s += part[4 + wave][g][lane];
        s += part[6 + wave][g][lane];
        z[g] = s;
      }
      float* hw;
      if (isB) hw = (t & 1) ? h1b1 : h1b0;      // h1buf[t&1]
      else     hw = (t & 1) ? h0b1 : h0b0;      // h0buf[t&1]
#pragma unroll
      for (int r = 0; r < 4; r++) {
        int m = me_base + r;
        float zi, zo, zf, zc;
        if (isB) {
          zi = z[0][r] + bi; zo = z[1][r] + bo; zf = z[2][r] + bf_; zc = z[3][r] + bc;
        } else {
          const float* zrow = Zx + (size_t)t * 262144 + (size_t)m * 2048;
          zi = z[0][r] + zrow[j];        zo = z[1][r] + zrow[512 + j];
          zf = z[2][r] + zrow[1024 + j]; zc = z[3][r] + zrow[1536 + j];
        }
        float iv = sigm(zi), ov = sigm(zo), fv = sigm(zf), cv = tanh_(zc);
        float cn = fv * cs[r] + iv * cv;
        float hn = ov * tanh_(cn);
        cs[r] = cn;
        // cross-XCD visible h write (sc1, relaxed agent atomic)
        __hip_atomic_store(&hw[m * 512 + j], hn, __ATOMIC_RELAXED, __HIP_MEMORY_SCOPE_AGENT);
        if (isB) H1all[((size_t)t * 128 + m) * 512 + j] = f2bf(hn);
        if (t == 31) {
          size_t o = OUT_H + (isB ? 131072 : 0) + (size_t)m * 1024;
          outHid[o + j] = hn;
          outHid[o + 512 + j] = cn;
        }
      }
    }
    if (p < 32) gridbar(bar, p + 1);
  }
}

extern "C" void kernel_launch(void* const* d_in, const int* in_sizes, int n_in,
                              void* d_out, int out_size, void* d_ws, size_t ws_size,
                              hipStream_t stream) {
  const float* cnn  = (const float*)d_in[0];
  const int*   tok  = (const int*)d_in[1];
  const float* chs  = (const float*)d_in[2];
  const float* emb  = (const float*)d_in[3];
  const float* W_in = (const float*)d_in[4];
  const float* b_in = (const float*)d_in[5];
  const float* W0   = (const float*)d_in[6];
  const float* b0   = (const float*)d_in[7];
  const float* W1   = (const float*)d_in[8];
  const float* b1   = (const float*)d_in[9];
  const float* W_out= (const float*)d_in[10];
  const float* b_out= (const float*)d_in[11];
  float* out = (float*)d_out;

  char* p = (char*)d_ws;
  auto alloc = [&](size_t bytes) { char* q = p; p += (bytes + 255) & ~(size_t)255; return q; };
  unsigned short* Win_t  = (unsigned short*)alloc((size_t)512 * 2048 * 2);
  unsigned short* W0e_t  = (unsigned short*)alloc((size_t)2048 * 512 * 2);
  unsigned short* W0m_t  = (unsigned short*)alloc((size_t)2048 * 512 * 2);
  unsigned short* W0h_t  = (unsigned short*)alloc((size_t)2048 * 512 * 2);
  unsigned short* W1_t   = (unsigned short*)alloc((size_t)2048 * 1024 * 2);
  unsigned short* Wout_t = (unsigned short*)alloc((size_t)10000 * 512 * 2);
  unsigned short* cnn_b  = (unsigned short*)alloc((size_t)128 * 2048 * 2);
  unsigned short* proc_b = (unsigned short*)alloc((size_t)128 * 512 * 2);
  float*          Cf     = (float*)alloc((size_t)128 * 2048 * 4);
  unsigned short* Xe     = (unsigned short*)alloc((size_t)4096 * 512 * 2);
  float*          Zx     = (float*)alloc((size_t)4096 * 2048 * 4);
  float*          h0b0   = (float*)alloc(65536 * 4);
  float*          h0b1   = (float*)alloc(65536 * 4);
  float*          h1b0   = (float*)alloc(65536 * 4);
  float*          h1b1   = (float*)alloc(65536 * 4);
  unsigned short* H1all  = (unsigned short*)alloc((size_t)4096 * 512 * 2);
  int*            bar    = (int*)alloc(4096 * 4);   // 256 slots x 16-int pad

  dim3 tb(32, 8);
  k_transpose_cvt<<<dim3(16, 64),  tb, 0, stream>>>(W_in, Win_t, 2048, 512);
  k_transpose_cvt<<<dim3(64, 16),  tb, 0, stream>>>(W0,               W0e_t, 512, 2048);
  k_transpose_cvt<<<dim3(64, 16),  tb, 0, stream>>>(W0 + 512 * 2048,  W0m_t, 512, 2048);
  k_transpose_cvt<<<dim3(64, 16),  tb, 0, stream>>>(W0 + 1024 * 2048, W0h_t, 512, 2048);
  k_transpose_cvt<<<dim3(64, 32),  tb, 0, stream>>>(W1, W1_t, 1024, 2048);
  k_transpose_cvt<<<dim3(313, 16), tb, 0, stream>>>(W_out, Wout_t, 512, 10000);
  k_cvt_bf16<<<256, 256, 0, stream>>>(cnn, cnn_b, 65536);

  // proc = leaky(cnn @ W_in + b_in)  (bf16 out)
  k_gemm<0><<<dim3(4, 1), 256, 0, stream>>>(cnn_b, Win_t, b_in, nullptr, nullptr, proc_b,
                                            128, 512, 2048);
  // Cf = proc @ W0[512:1024] + b0  (fp32, per-batch broadcast term of Zx)
  k_gemm<1><<<dim3(16, 1), 256, 0, stream>>>(proc_b, W0m_t, b0, nullptr, Cf, nullptr,
                                             128, 2048, 512);
  k_gather_emb<<<2048, 256, 0, stream>>>(emb, tok, Xe);
  // Zx[t*128+b] = emb_t @ W0[0:512] + Cf[b]
  k_gemm<2><<<dim3(16, 32), 256, 0, stream>>>(Xe, W0e_t, nullptr, Cf, Zx, nullptr,
                                              4096, 2048, 512);
  k_init2<<<256, 256, 0, stream>>>(chs, h0b1, h1b1, bar);

  // whole recurrence: one persistent kernel, 33 phases, 32 grid barriers
  k_lstm<<<256, 256, 0, stream>>>(W0h_t, W1_t, Zx, b1, chs,
                                  h0b0, h0b1, h1b0, h1b1, H1all, out, bar);

  // logits = H1all @ W_out + b_out  -> d_out[(b*32+t)*10000 + v]
  k_gemm<3><<<dim3(79, 32), 256, 0, stream>>>(H1all, Wout_t, b_out, nullptr, out, nullptr,
                                              4096, 10000, 512);
}